// Round 6
// baseline (404.116 us; speedup 1.0000x reference)
//
#include <hip/hip_runtime.h>
#include <hip/hip_bf16.h>

#define B_ 128
#define T_ 512
#define L_ 256

// v_dot2_f32_bf16: D = S0.bf16[0]*S1.bf16[0] + S0.bf16[1]*S1.bf16[1] + S2
__device__ __forceinline__ float dot2bf16(unsigned a, unsigned b, float c) {
    float d;
    asm("v_dot2_f32_bf16 %0, %1, %2, %3" : "=v"(d) : "v"(a), "v"(b), "v"(c));
    return d;
}

__device__ __forceinline__ unsigned short f2bf(float x) {  // RNE f32->bf16
    unsigned u = __builtin_bit_cast(unsigned, x);
    return (unsigned short)((u + 0x7fff + ((u >> 16) & 1)) >> 16);
}

// ---------------------------------------------------------------------------
// Kernel A: ETg[m][l] = bf16(exp(trans[l][m]))  (transposed)
// ---------------------------------------------------------------------------
__global__ __launch_bounds__(256) void k_exptrans(const float* __restrict__ trans,
                                                  unsigned short* __restrict__ ETg) {
    int m = blockIdx.x, l = threadIdx.x;
    ETg[m * L_ + l] = f2bf(__expf(trans[l * L_ + m]));
}

// ---------------------------------------------------------------------------
// Kernel B: labels from one-hot y_true (one wave per row)
// ---------------------------------------------------------------------------
__global__ __launch_bounds__(256) void k_labels(const float* __restrict__ y_true,
                                                int* __restrict__ labels) {
    int wid = threadIdx.x >> 6, lane = threadIdx.x & 63;
    int r = blockIdx.x * 4 + wid;
    const float4* row = (const float4*)(y_true + (size_t)r * L_);
    float4 v = row[lane];
    int loc = -1;
    if (v.x > 0.5f) loc = lane * 4 + 0;
    if (v.y > 0.5f) loc = lane * 4 + 1;
    if (v.z > 0.5f) loc = lane * 4 + 2;
    if (v.w > 0.5f) loc = lane * 4 + 3;
    unsigned long long m = __ballot(loc >= 0);
    int src = __ffsll(m) - 1;
    int lab = __shfl(loc, src, 64);
    if (lane == 0) labels[r] = lab;
}

// ---------------------------------------------------------------------------
// Kernel C: path_score
// ---------------------------------------------------------------------------
__global__ __launch_bounds__(256) void k_path(const float* __restrict__ y_pre,
                                              const float* __restrict__ trans,
                                              const int* __restrict__ labels,
                                              float* __restrict__ path) {
    int b = blockIdx.x, tid = threadIdx.x;
    const int* lb = labels + b * T_;
    float acc = 0.f;
    for (int t = tid; t < T_; t += 256) {
        int l1 = lb[t];
        acc += y_pre[((size_t)b * T_ + t) * L_ + l1];
        if (t + 1 < T_) acc += trans[l1 * L_ + lb[t + 1]];
    }
#pragma unroll
    for (int off = 1; off < 64; off <<= 1) acc += __shfl_xor(acc, off, 64);
    __shared__ float red[4];
    int wid = tid >> 6, lane = tid & 63;
    if (lane == 0) red[wid] = acc;
    __syncthreads();
    if (tid == 0) path[b] = red[0] + red[1] + red[2] + red[3];
}

// ---------------------------------------------------------------------------
// Kernel D: forward recursion, 4-way l-split, ET register-resident.
// Only the register file can feed 128 dot2/thread/step (LDS and L2 are both
// >=4x too slow). Rounds 1-4: LLVM sank the ET loads into the loop (legal
// for const __restrict__ memory) -> 128KB/CU/step L2 refetch. Fix here:
// asm VOLATILE keep-alives on the SCALAR components (whole-uint4 tie is
// unsupported: "tied indirect register inputs"). Volatile defs cannot be
// sunk/remat'ed, and "+v" makes the post-asm value asm-defined, so the
// only legal codegen is keeping the 128 ET VGPRs live across the loop.
// ---------------------------------------------------------------------------
__global__ void
__attribute__((amdgpu_flat_work_group_size(256, 256), amdgpu_waves_per_eu(1, 1)))
k_forward(const float* __restrict__ yp_all,
          const unsigned short* __restrict__ ETg,
          const float* __restrict__ path,
          float* __restrict__ out) {
    int b = blockIdx.x, tid = threadIdx.x;
    int c = tid >> 6;          // wave id = l-chunk
    int i = tid & 63;          // lane
    int m_own = (c << 6) | i;
    const float* yp = yp_all + (size_t)b * T_ * L_;

    // 4 row-chunks -> 32 uint4 = 128 VGPRs
    uint4 R[4][8];
#pragma unroll
    for (int r = 0; r < 4; ++r) {
        const uint4* src = (const uint4*)(ETg + (size_t)(i + 64 * r) * L_ + 64 * c);
#pragma unroll
        for (int j = 0; j < 8; ++j) R[r][j] = src[j];
    }
    // VOLATILE pin, scalar components (single-register ties are supported)
#pragma unroll
    for (int r = 0; r < 4; ++r)
#pragma unroll
        for (int j = 0; j < 8; ++j)
            asm volatile("" : "+v"(R[r][j].x), "+v"(R[r][j].y),
                              "+v"(R[r][j].z), "+v"(R[r][j].w));

    __shared__ unsigned short ph[2][L_];   // p (bf16), double-buffered
    __shared__ float pj[L_ * 5];           // partials, padded stride 5 dwords
    __shared__ float red[4];
    __shared__ float nmr[2];               // sampled normalizer, 2 slots

    float s = yp[m_own];                   // s_0 = y_pre[b,0,:]

    {   // exact initial max (once)
        float v = s;
#pragma unroll
        for (int off = 1; off < 64; off <<= 1) v = fmaxf(v, __shfl_xor(v, off, 64));
        if (i == 0) red[c] = v;
        __syncthreads();
        if (tid == 0) {
            float M = fmaxf(fmaxf(red[0], red[1]), fmaxf(red[2], red[3]));
            nmr[0] = M; nmr[1] = M;
        }
        __syncthreads();
    }

    // emit prefetched TWO steps ahead (HBM miss latency ~900cy > step time)
    float emit   = yp[(size_t)1 * L_ + m_own];   // for t=1
    float emit1  = yp[(size_t)2 * L_ + m_own];   // for t=2

    for (int t = 1; t < T_; ++t) {
        // ---- phase A ----
        float N = nmr[t & 1];              // broadcast read (lag-2 sample)
        int tpf = (t + 3 <= T_ - 1) ? (t + 3) : (T_ - 1);
        float emit2 = yp[(size_t)tpf * L_ + m_own];   // for t+2
        ph[t & 1][m_own] = f2bf(__expf(s - N));
        __syncthreads();                   // barrier 1: p visible

        // ---- phase B: 4 partial dots over own l-chunk ----
        const uint4* P = (const uint4*)(&ph[t & 1][c << 6]);
        float a0 = 0, a1 = 0, a2 = 0, a3 = 0;
        float b0 = 0, b1 = 0, b2 = 0, b3 = 0;
#pragma unroll
        for (int j = 0; j < 8; ++j) {
            uint4 Pv = P[j];               // uniform b128 (128-B chunk)
            a0 = dot2bf16(Pv.x, R[0][j].x, a0); b0 = dot2bf16(Pv.y, R[0][j].y, b0);
            a0 = dot2bf16(Pv.z, R[0][j].z, a0); b0 = dot2bf16(Pv.w, R[0][j].w, b0);
            a1 = dot2bf16(Pv.x, R[1][j].x, a1); b1 = dot2bf16(Pv.y, R[1][j].y, b1);
            a1 = dot2bf16(Pv.z, R[1][j].z, a1); b1 = dot2bf16(Pv.w, R[1][j].w, b1);
            a2 = dot2bf16(Pv.x, R[2][j].x, a2); b2 = dot2bf16(Pv.y, R[2][j].y, b2);
            a2 = dot2bf16(Pv.z, R[2][j].z, a2); b2 = dot2bf16(Pv.w, R[2][j].w, b2);
            a3 = dot2bf16(Pv.x, R[3][j].x, a3); b3 = dot2bf16(Pv.y, R[3][j].y, b3);
            a3 = dot2bf16(Pv.z, R[3][j].z, a3); b3 = dot2bf16(Pv.w, R[3][j].w, b3);
        }
        pj[(i      ) * 5 + c] = a0 + b0;
        pj[(i +  64) * 5 + c] = a1 + b1;
        pj[(i + 128) * 5 + c] = a2 + b2;
        pj[(i + 192) * 5 + c] = a3 + b3;
        __syncthreads();                   // barrier 2: partials visible

        // ---- phase C: combine, advance state ----
        int base = m_own * 5;
        float sum = (pj[base] + pj[base + 1]) + (pj[base + 2] + pj[base + 3]);
        s = N + __logf(sum) + emit;
        emit = emit1; emit1 = emit2;
        if (tid == 0) nmr[t & 1] = s;      // sample for step t+2
    }

    // final logsumexp over m
    __syncthreads();
    float v = s;
#pragma unroll
    for (int off = 1; off < 64; off <<= 1) v = fmaxf(v, __shfl_xor(v, off, 64));
    if (i == 0) red[c] = v;
    __syncthreads();
    float M = fmaxf(fmaxf(red[0], red[1]), fmaxf(red[2], red[3]));
    float e = __expf(s - M);
    v = e;
#pragma unroll
    for (int off = 1; off < 64; off <<= 1) v += __shfl_xor(v, off, 64);
    __syncthreads();
    if (i == 0) red[c] = v;
    __syncthreads();
    if (tid == 0) out[b] = M + __logf(red[0] + red[1] + red[2] + red[3]) - path[b];
}

// ---------------------------------------------------------------------------
extern "C" void kernel_launch(void* const* d_in, const int* in_sizes, int n_in,
                              void* d_out, int out_size, void* d_ws, size_t ws_size,
                              hipStream_t stream) {
    const float* y_true = (const float*)d_in[0];
    const float* y_pre  = (const float*)d_in[1];
    const float* trans  = (const float*)d_in[2];
    float* out = (float*)d_out;

    char* ws = (char*)d_ws;
    unsigned short* ETg = (unsigned short*)ws;            // 128 KiB
    int* labels = (int*)(ws + 131072);                    // 256 KiB
    float* path = (float*)(ws + 131072 + 262144);         // 512 B

    hipLaunchKernelGGL(k_exptrans, dim3(L_), dim3(L_), 0, stream, trans, ETg);
    hipLaunchKernelGGL(k_labels, dim3(B_ * T_ / 4), dim3(256), 0, stream, y_true, labels);
    hipLaunchKernelGGL(k_path, dim3(B_), dim3(256), 0, stream, y_pre, trans, labels, path);
    hipLaunchKernelGGL(k_forward, dim3(B_), dim3(256), 0, stream, y_pre, ETg, path, out);
}

// Round 7
// 389.274 us; speedup vs baseline: 1.0381x; 1.0381x over previous
//
#include <hip/hip_runtime.h>
#include <hip/hip_bf16.h>

#define B_ 128
#define T_ 512
#define L_ 256

// v_dot2_f32_bf16: D = S0.bf16[0]*S1.bf16[0] + S0.bf16[1]*S1.bf16[1] + S2
__device__ __forceinline__ float dot2bf16(unsigned a, unsigned b, float c) {
    float d;
    asm("v_dot2_f32_bf16 %0, %1, %2, %3" : "=v"(d) : "v"(a), "v"(b), "v"(c));
    return d;
}

__device__ __forceinline__ unsigned short f2bf(float x) {  // RNE f32->bf16
    unsigned u = __builtin_bit_cast(unsigned, x);
    return (unsigned short)((u + 0x7fff + ((u >> 16) & 1)) >> 16);
}

// ---------------------------------------------------------------------------
// Kernel A: ETg[m][l] = bf16(exp(trans[l][m]))  (transposed)
// ---------------------------------------------------------------------------
__global__ __launch_bounds__(256) void k_exptrans(const float* __restrict__ trans,
                                                  unsigned short* __restrict__ ETg) {
    int m = blockIdx.x, l = threadIdx.x;
    ETg[m * L_ + l] = f2bf(__expf(trans[l * L_ + m]));
}

// ---------------------------------------------------------------------------
// Kernel B: labels from one-hot y_true (one wave per row)
// ---------------------------------------------------------------------------
__global__ __launch_bounds__(256) void k_labels(const float* __restrict__ y_true,
                                                int* __restrict__ labels) {
    int wid = threadIdx.x >> 6, lane = threadIdx.x & 63;
    int r = blockIdx.x * 4 + wid;
    const float4* row = (const float4*)(y_true + (size_t)r * L_);
    float4 v = row[lane];
    int loc = -1;
    if (v.x > 0.5f) loc = lane * 4 + 0;
    if (v.y > 0.5f) loc = lane * 4 + 1;
    if (v.z > 0.5f) loc = lane * 4 + 2;
    if (v.w > 0.5f) loc = lane * 4 + 3;
    unsigned long long m = __ballot(loc >= 0);
    int src = __ffsll(m) - 1;
    int lab = __shfl(loc, src, 64);
    if (lane == 0) labels[r] = lab;
}

// ---------------------------------------------------------------------------
// Kernel C: path_score
// ---------------------------------------------------------------------------
__global__ __launch_bounds__(256) void k_path(const float* __restrict__ y_pre,
                                              const float* __restrict__ trans,
                                              const int* __restrict__ labels,
                                              float* __restrict__ path) {
    int b = blockIdx.x, tid = threadIdx.x;
    const int* lb = labels + b * T_;
    float acc = 0.f;
    for (int t = tid; t < T_; t += 256) {
        int l1 = lb[t];
        acc += y_pre[((size_t)b * T_ + t) * L_ + l1];
        if (t + 1 < T_) acc += trans[l1 * L_ + lb[t + 1]];
    }
#pragma unroll
    for (int off = 1; off < 64; off <<= 1) acc += __shfl_xor(acc, off, 64);
    __shared__ float red[4];
    int wid = tid >> 6, lane = tid & 63;
    if (lane == 0) red[wid] = acc;
    __syncthreads();
    if (tid == 0) path[b] = red[0] + red[1] + red[2] + red[3];
}

// ---------------------------------------------------------------------------
// Kernel D: forward recursion, 8-wave 8-way l-split.
// Rounds 1-6 lesson: the VGPR allocator budget stays ~128 regardless of
// launch_bounds/waves_per_eu attributes; a 128-VGPR ET block gets spilled to
// scratch and re-read every step (the whole bottleneck). Fix: 512 threads,
// thread (c,i) owns 4 rows x 32-l-chunk = 64 VGPRs of ET -> total demand
// ~95 < 128 budget -> no spill. Volatile scalar pins block load-sinking.
// VALU floor unchanged (issue-bound); LDS p-reads stay broadcast.
// Partials: pj[row*9 + c] (stride 9 -> 2 lanes/bank = free).
// ---------------------------------------------------------------------------
__global__ void __launch_bounds__(512, 2)
k_forward(const float* __restrict__ yp_all,
          const unsigned short* __restrict__ ETg,
          const float* __restrict__ path,
          float* __restrict__ out) {
    int b = blockIdx.x, tid = threadIdx.x;
    int c = tid >> 6;          // wave id = l-chunk [32c, 32c+32)
    int i = tid & 63;          // lane; owned rows {i, i+64, i+128, i+192}
    const float* yp = yp_all + (size_t)b * T_ * L_;

    // ET: 4 rows x 32 l = 16 uint4 = 64 VGPRs
    uint4 R[4][4];
#pragma unroll
    for (int r = 0; r < 4; ++r) {
        const uint4* src = (const uint4*)(ETg + (size_t)(i + 64 * r) * L_ + 32 * c);
#pragma unroll
        for (int j = 0; j < 4; ++j) R[r][j] = src[j];
    }
#pragma unroll
    for (int r = 0; r < 4; ++r)
#pragma unroll
        for (int j = 0; j < 4; ++j)
            asm volatile("" : "+v"(R[r][j].x), "+v"(R[r][j].y),
                              "+v"(R[r][j].z), "+v"(R[r][j].w));

    __shared__ alignas(16) unsigned short ph[2][L_];   // p (bf16), dbuf
    __shared__ float pj[L_ * 9];                       // partials, stride 9
    __shared__ float red[8];
    __shared__ float nmr[2];                           // sampled normalizer

    const bool owner = tid < L_;   // waves 0-3 own one state each
    const int m = tid;

    float s = 0.f, emit = 0.f, emit1 = 0.f;
    if (owner) s = yp[m];          // s_0 = y_pre[b,0,:]

    {   // exact initial max over 256 states (once)
        float v = owner ? s : -3.4e38f;
#pragma unroll
        for (int off = 1; off < 64; off <<= 1) v = fmaxf(v, __shfl_xor(v, off, 64));
        if (i == 0) red[c] = v;
        __syncthreads();
        if (tid == 0) {
            float M = fmaxf(fmaxf(red[0], red[1]), fmaxf(red[2], red[3]));
            nmr[0] = M; nmr[1] = M;
        }
        __syncthreads();
    }

    if (owner) {
        emit  = yp[(size_t)1 * L_ + m];   // E(1)
        emit1 = yp[(size_t)2 * L_ + m];   // E(2)
    }

    for (int t = 1; t < T_; ++t) {
        // ---- phase A (owners): normalize + publish p ----
        float N = 0.f, emit2 = 0.f;
        if (owner) {
            N = nmr[t & 1];                               // s_{t-2}[0] sample
            int tpf = (t + 2 <= T_ - 1) ? (t + 2) : (T_ - 1);
            emit2 = yp[(size_t)tpf * L_ + m];             // E(t+2)  [bugfix]
            ph[t & 1][m] = f2bf(__expf(s - N));
        }
        __syncthreads();                   // barrier 1: p visible

        // ---- phase B (all 512): partial dots over own 32-l-chunk ----
        const uint4* P = ((const uint4*)&ph[t & 1][0]) + (c << 2);
        float a0=0,a1=0,a2=0,a3=0,b0=0,b1=0,b2=0,b3=0;
#pragma unroll
        for (int j = 0; j < 4; ++j) {
            uint4 Pv = P[j];               // uniform b128 (64-B chunk)
            a0 = dot2bf16(Pv.x, R[0][j].x, a0); b0 = dot2bf16(Pv.y, R[0][j].y, b0);
            a0 = dot2bf16(Pv.z, R[0][j].z, a0); b0 = dot2bf16(Pv.w, R[0][j].w, b0);
            a1 = dot2bf16(Pv.x, R[1][j].x, a1); b1 = dot2bf16(Pv.y, R[1][j].y, b1);
            a1 = dot2bf16(Pv.z, R[1][j].z, a1); b1 = dot2bf16(Pv.w, R[1][j].w, b1);
            a2 = dot2bf16(Pv.x, R[2][j].x, a2); b2 = dot2bf16(Pv.y, R[2][j].y, b2);
            a2 = dot2bf16(Pv.z, R[2][j].z, a2); b2 = dot2bf16(Pv.w, R[2][j].w, b2);
            a3 = dot2bf16(Pv.x, R[3][j].x, a3); b3 = dot2bf16(Pv.y, R[3][j].y, b3);
            a3 = dot2bf16(Pv.z, R[3][j].z, a3); b3 = dot2bf16(Pv.w, R[3][j].w, b3);
        }
        pj[(i      ) * 9 + c] = a0 + b0;
        pj[(i +  64) * 9 + c] = a1 + b1;
        pj[(i + 128) * 9 + c] = a2 + b2;
        pj[(i + 192) * 9 + c] = a3 + b3;
        __syncthreads();                   // barrier 2: partials visible

        // ---- phase C (owners): combine 8 partials, advance state ----
        if (owner) {
            const float* q = &pj[m * 9];
            float sum = ((q[0] + q[1]) + (q[2] + q[3]))
                      + ((q[4] + q[5]) + (q[6] + q[7]));
            s = N + __logf(sum) + emit;
            emit = emit1; emit1 = emit2;
            if (tid == 0) nmr[t & 1] = s;  // sample for step t+2
        }
    }

    // ---- final logsumexp over m ----
    __syncthreads();
    {
        float v = owner ? s : -3.4e38f;
#pragma unroll
        for (int off = 1; off < 64; off <<= 1) v = fmaxf(v, __shfl_xor(v, off, 64));
        if (i == 0) red[c] = v;
    }
    __syncthreads();
    float M = fmaxf(fmaxf(red[0], red[1]), fmaxf(red[2], red[3]));
    float e = owner ? __expf(s - M) : 0.f;
    float v = e;
#pragma unroll
    for (int off = 1; off < 64; off <<= 1) v += __shfl_xor(v, off, 64);
    __syncthreads();   // protect red[] reuse
    if (i == 0) red[c] = v;
    __syncthreads();
    if (tid == 0)
        out[b] = M + __logf((red[0] + red[1]) + (red[2] + red[3])) - path[b];
}

// ---------------------------------------------------------------------------
extern "C" void kernel_launch(void* const* d_in, const int* in_sizes, int n_in,
                              void* d_out, int out_size, void* d_ws, size_t ws_size,
                              hipStream_t stream) {
    const float* y_true = (const float*)d_in[0];
    const float* y_pre  = (const float*)d_in[1];
    const float* trans  = (const float*)d_in[2];
    float* out = (float*)d_out;

    char* ws = (char*)d_ws;
    unsigned short* ETg = (unsigned short*)ws;            // 128 KiB
    int* labels = (int*)(ws + 131072);                    // 256 KiB
    float* path = (float*)(ws + 131072 + 262144);         // 512 B

    hipLaunchKernelGGL(k_exptrans, dim3(L_), dim3(L_), 0, stream, trans, ETg);
    hipLaunchKernelGGL(k_labels, dim3(B_ * T_ / 4), dim3(256), 0, stream, y_true, labels);
    hipLaunchKernelGGL(k_path, dim3(B_), dim3(256), 0, stream, y_pre, trans, labels, path);
    hipLaunchKernelGGL(k_forward, dim3(B_), dim3(512), 0, stream, y_pre, ETg, path, out);
}